// Round 1
// baseline (182.615 us; speedup 1.0000x reference)
//
#include <hip/hip_runtime.h>
#include <hip/hip_bf16.h>
#include <cstdint>

// ---------------- problem constants ----------------
#define BB 1024          // batch
#define DD 512           // dim
#define CC 50000         // classes
#define NT 782           // ceil(50000/64) n-tiles
#define SCALE_F 64.0f
#define COS_M_F 0.87758256189037276f
#define SIN_M_F 0.47942553860420301f
#define TH_F   (-0.87758256189037276f)
#define MM_F   0.23971276930210156f

typedef __attribute__((ext_vector_type(8))) short short8;
typedef __attribute__((ext_vector_type(8))) unsigned short ushort8;
typedef __attribute__((ext_vector_type(4))) float f32x4;

__device__ __forceinline__ unsigned short f2bf(float x) {
    union { __hip_bfloat16 h; unsigned short u; } v;
    v.h = __float2bfloat16(x);
    return v.u;
}

// ---------------- ws layout (bytes) ----------------
// e_bf16 : [1024][512] ushort        @ 0          (1,048,576)
// inv_wn : [50000] float             @ 0x100000   (200,000 -> pad 204,800)
// part_m : [1024][NT] float          @ 0x132000   (3,203,072)
// part_s : [1024][NT] float          @ next
// lab_lg : [1024] float
// nll    : [1024] float
#define OFF_E    ((size_t)0)
#define OFF_INV  ((size_t)(1u<<20))
#define OFF_PM   (OFF_INV + 204800)
#define OFF_PS   (OFF_PM + (size_t)BB*NT*4)
#define OFF_LAB  (OFF_PS + (size_t)BB*NT*4)
#define OFF_NLL  (OFF_LAB + 4096)

// ---------------- kernel 1: normalize embeddings -> bf16 ----------------
__global__ void norm_e_kernel(const float* __restrict__ e, unsigned short* __restrict__ ebf) {
    const int b = blockIdx.x;          // 1024 blocks
    const int l = threadIdx.x;         // 64 threads
    const float4* row = reinterpret_cast<const float4*>(e + (size_t)b * DD);
    float4 v0 = row[l * 2 + 0];
    float4 v1 = row[l * 2 + 1];
    float s = v0.x*v0.x + v0.y*v0.y + v0.z*v0.z + v0.w*v0.w
            + v1.x*v1.x + v1.y*v1.y + v1.z*v1.z + v1.w*v1.w;
    #pragma unroll
    for (int m = 1; m < 64; m <<= 1) s += __shfl_xor(s, m);
    float inv = 1.0f / fmaxf(sqrtf(s), 1e-12f);
    ushort8 h;
    h[0]=f2bf(v0.x*inv); h[1]=f2bf(v0.y*inv); h[2]=f2bf(v0.z*inv); h[3]=f2bf(v0.w*inv);
    h[4]=f2bf(v1.x*inv); h[5]=f2bf(v1.y*inv); h[6]=f2bf(v1.z*inv); h[7]=f2bf(v1.w*inv);
    reinterpret_cast<ushort8*>(ebf + (size_t)b * DD)[l] = h;
}

// ---------------- kernel 2: weight inverse norms ----------------
__global__ void wnorm_kernel(const float* __restrict__ w, float* __restrict__ invn) {
    const int row = blockIdx.x * 4 + (threadIdx.x >> 6);   // 12500 blocks * 4 waves
    const int l = threadIdx.x & 63;
    const float4* r = reinterpret_cast<const float4*>(w + (size_t)row * DD);
    float4 v0 = r[l * 2 + 0];
    float4 v1 = r[l * 2 + 1];
    float s = v0.x*v0.x + v0.y*v0.y + v0.z*v0.z + v0.w*v0.w
            + v1.x*v1.x + v1.y*v1.y + v1.z*v1.z + v1.w*v1.w;
    #pragma unroll
    for (int m = 1; m < 64; m <<= 1) s += __shfl_xor(s, m);
    if (l == 0) invn[row] = 1.0f / fmaxf(sqrtf(s), 1e-12f);
}

// ---------------- kernel 3: fused GEMM + arcface + partial logsumexp ----------------
// tile: BM=256 x BN=64 x BK=64, 4 waves (each wave: 64 rows x 64 cols, acc 4x4 frags)
__global__ __launch_bounds__(256) void arc_gemm_kernel(
        const unsigned short* __restrict__ ebf,  // [1024][512] bf16 normalized
        const float* __restrict__ wgt,           // [50000][512] fp32 raw
        const float* __restrict__ invw,          // [50000]
        const int* __restrict__ labels,          // [1024]
        float* __restrict__ part_m,              // [1024][NT]
        float* __restrict__ part_s,              // [1024][NT]
        float* __restrict__ lab_logit)           // [1024]
{
    __shared__ __align__(16) char ldsA[256 * 128];   // 256 rows x 64 bf16 (swizzled)
    __shared__ __align__(16) char ldsB[64 * 128];    // 64 cols x 64 bf16 (swizzled)
    __shared__ int lds_lab[256];

    const int t  = threadIdx.x;
    const int wv = t >> 6;
    const int l  = t & 63;
    const int r16 = l & 15;
    const int kg  = l >> 4;
    const int bn = blockIdx.x;            // n tile (0..NT-1)
    const int m0 = blockIdx.y * 256;      // row base
    const int c0 = bn * 64;               // col base

    lds_lab[t] = labels[m0 + t];

    f32x4 acc[4][4];
    #pragma unroll
    for (int m = 0; m < 4; ++m)
        #pragma unroll
        for (int n = 0; n < 4; ++n)
            acc[m][n] = (f32x4){0.f, 0.f, 0.f, 0.f};

    for (int kt = 0; kt < 8; ++kt) {
        // ---- stage A (bf16, global_load_lds w/ pre-swizzled source) ----
        #pragma unroll
        for (int i = 0; i < 8; ++i) {
            int flat = (i * 256 + t) * 16;
            int row  = flat >> 7;
            int col  = (flat & 127) ^ ((row & 7) << 4);
            const char* src = reinterpret_cast<const char*>(ebf)
                            + (size_t)(m0 + row) * (DD * 2) + kt * 128 + col;
            __builtin_amdgcn_global_load_lds(
                (__attribute__((address_space(1))) void*)(src),
                (__attribute__((address_space(3))) void*)(ldsA + flat),
                16, 0, 0);
        }
        // ---- stage B (fp32 -> *invnorm -> bf16, swizzled ds_write) ----
        #pragma unroll
        for (int i = 0; i < 2; ++i) {
            int chunk = i * 256 + t;       // 0..511
            int brow  = chunk >> 3;        // class within tile
            int cb    = chunk & 7;         // 16B chunk within row
            int cls   = c0 + brow;
            ushort8 hv = (ushort8){0,0,0,0,0,0,0,0};
            if (cls < CC) {
                float inv = invw[cls];
                const float4* src = reinterpret_cast<const float4*>(
                    wgt + (size_t)cls * DD + kt * 64 + cb * 8);
                float4 f0 = src[0];
                float4 f1 = src[1];
                hv[0]=f2bf(f0.x*inv); hv[1]=f2bf(f0.y*inv);
                hv[2]=f2bf(f0.z*inv); hv[3]=f2bf(f0.w*inv);
                hv[4]=f2bf(f1.x*inv); hv[5]=f2bf(f1.y*inv);
                hv[6]=f2bf(f1.z*inv); hv[7]=f2bf(f1.w*inv);
            }
            int dst = brow * 128 + ((cb * 16) ^ ((brow & 7) << 4));
            *reinterpret_cast<ushort8*>(ldsB + dst) = hv;
        }
        __syncthreads();
        // ---- MFMA ----
        #pragma unroll
        for (int kk = 0; kk < 2; ++kk) {
            const int kb = kk * 64 + kg * 16;
            short8 a[4], b[4];
            #pragma unroll
            for (int m = 0; m < 4; ++m) {
                int row = wv * 64 + m * 16 + r16;
                a[m] = *reinterpret_cast<const short8*>(ldsA + row * 128 + (kb ^ ((row & 7) << 4)));
            }
            #pragma unroll
            for (int n = 0; n < 4; ++n) {
                int row = n * 16 + r16;
                b[n] = *reinterpret_cast<const short8*>(ldsB + row * 128 + (kb ^ ((row & 7) << 4)));
            }
            #pragma unroll
            for (int m = 0; m < 4; ++m)
                #pragma unroll
                for (int n = 0; n < 4; ++n)
                    acc[m][n] = __builtin_amdgcn_mfma_f32_16x16x32_bf16(a[m], b[n], acc[m][n], 0, 0, 0);
        }
        __syncthreads();
    }

    // ---- epilogue: logits, per-row max + sum(exp) over this 64-col tile ----
    #pragma unroll
    for (int m = 0; m < 4; ++m) {
        #pragma unroll
        for (int j = 0; j < 4; ++j) {
            const int row_local = wv * 64 + m * 16 + kg * 4 + j;
            const int lab = lds_lab[row_local];
            float vals[4];
            float vmax = -1e30f;
            #pragma unroll
            for (int n = 0; n < 4; ++n) {
                float cosv = acc[m][n][j];
                int col = c0 + n * 16 + r16;
                float logit;
                if (col < CC) {
                    logit = SCALE_F * cosv;
                    if (col == lab) {
                        float c2 = fminf(fmaxf(cosv * cosv, 0.f), 1.f);
                        float phi = cosv * COS_M_F - sqrtf(1.f - c2) * SIN_M_F;
                        phi = (cosv > TH_F) ? phi : (cosv - MM_F);
                        logit = SCALE_F * phi;
                        lab_logit[m0 + row_local] = logit;
                    }
                } else {
                    logit = -1e30f;
                }
                vals[n] = logit;
                vmax = fmaxf(vmax, logit);
            }
            #pragma unroll
            for (int mk = 1; mk < 16; mk <<= 1) vmax = fmaxf(vmax, __shfl_xor(vmax, mk));
            float s = 0.f;
            #pragma unroll
            for (int n = 0; n < 4; ++n) s += __expf(vals[n] - vmax);
            #pragma unroll
            for (int mk = 1; mk < 16; mk <<= 1) s += __shfl_xor(s, mk);
            if (r16 == 0) {
                size_t idx = (size_t)(m0 + row_local) * NT + bn;
                part_m[idx] = vmax;
                part_s[idx] = s;
            }
        }
    }
}

// ---------------- kernel 4: per-row logsumexp merge -> nll ----------------
__global__ void row_lse_kernel(const float* __restrict__ part_m,
                               const float* __restrict__ part_s,
                               const float* __restrict__ lab_logit,
                               float* __restrict__ nll) {
    const int row = blockIdx.x;
    const int t = threadIdx.x;   // 256
    const float* pm = part_m + (size_t)row * NT;
    const float* ps = part_s + (size_t)row * NT;
    float M = -1e30f;
    for (int i = t; i < NT; i += 256) M = fmaxf(M, pm[i]);
    #pragma unroll
    for (int m = 1; m < 64; m <<= 1) M = fmaxf(M, __shfl_xor(M, m));
    __shared__ float redm[4];
    if ((t & 63) == 0) redm[t >> 6] = M;
    __syncthreads();
    M = fmaxf(fmaxf(redm[0], redm[1]), fmaxf(redm[2], redm[3]));
    float S = 0.f;
    for (int i = t; i < NT; i += 256) S += ps[i] * __expf(pm[i] - M);
    #pragma unroll
    for (int m = 1; m < 64; m <<= 1) S += __shfl_xor(S, m);
    __shared__ float reds[4];
    if ((t & 63) == 0) reds[t >> 6] = S;
    __syncthreads();
    if (t == 0) {
        float Sf = reds[0] + reds[1] + reds[2] + reds[3];
        nll[row] = -(lab_logit[row] - M - logf(Sf));
    }
}

// ---------------- kernel 5: mean over 1024 -> scalar ----------------
__global__ void mean_kernel(const float* __restrict__ nll, float* __restrict__ out) {
    const int t = threadIdx.x;  // 1024
    float v = nll[t];
    #pragma unroll
    for (int m = 1; m < 64; m <<= 1) v += __shfl_xor(v, m);
    __shared__ float red[16];
    if ((t & 63) == 0) red[t >> 6] = v;
    __syncthreads();
    if (t == 0) {
        float s = 0.f;
        #pragma unroll
        for (int i = 0; i < 16; ++i) s += red[i];
        out[0] = s * (1.0f / BB);
    }
}

// ---------------- launcher ----------------
extern "C" void kernel_launch(void* const* d_in, const int* in_sizes, int n_in,
                              void* d_out, int out_size, void* d_ws, size_t ws_size,
                              hipStream_t stream) {
    const float* emb    = (const float*)d_in[0];
    const int*   labels = (const int*)d_in[1];
    const float* wgt    = (const float*)d_in[2];
    float* out = (float*)d_out;
    char* ws = (char*)d_ws;

    unsigned short* ebf = (unsigned short*)(ws + OFF_E);
    float* invw   = (float*)(ws + OFF_INV);
    float* pm     = (float*)(ws + OFF_PM);
    float* ps     = (float*)(ws + OFF_PS);
    float* lablg  = (float*)(ws + OFF_LAB);
    float* nll    = (float*)(ws + OFF_NLL);

    norm_e_kernel<<<BB, 64, 0, stream>>>(emb, ebf);
    wnorm_kernel<<<CC / 4, 256, 0, stream>>>(wgt, invw);
    dim3 g3(NT, BB / 256);
    arc_gemm_kernel<<<g3, 256, 0, stream>>>(ebf, wgt, invw, labels, pm, ps, lablg);
    row_lse_kernel<<<BB, 256, 0, stream>>>(pm, ps, lablg, nll);
    mean_kernel<<<1, 1024, 0, stream>>>(nll, out);
}

// Round 2
// 148.622 us; speedup vs baseline: 1.2287x; 1.2287x over previous
//
#include <hip/hip_runtime.h>
#include <hip/hip_bf16.h>
#include <cstdint>

// ---------------- problem constants ----------------
#define BB 1024          // batch
#define DD 512           // dim
#define CC 50000         // classes
#define NT 782           // ceil(50000/64) n-tiles
#define NBLK 3128        // NT * 4 m-tiles (= 8 * 391, exactly divisible by 8 XCDs)
#define SCALE_F 64.0f
#define COS_M_F 0.87758256189037276f
#define SIN_M_F 0.47942553860420301f
#define TH_F   (-0.87758256189037276f)
#define MM_F   0.23971276930210156f

typedef __attribute__((ext_vector_type(8))) short short8;
typedef __attribute__((ext_vector_type(8))) unsigned short ushort8;
typedef __attribute__((ext_vector_type(4))) float f32x4;

__device__ __forceinline__ unsigned short f2bf(float x) {
    union { __hip_bfloat16 h; unsigned short u; } v;
    v.h = __float2bfloat16(x);
    return v.u;
}

// ---------------- ws layout (bytes) ----------------
#define OFF_PM   ((size_t)0)                          // [1024][NT] float
#define OFF_PS   (OFF_PM + (size_t)BB*NT*4)           // [1024][NT] float
#define OFF_LAB  (OFF_PS + (size_t)BB*NT*4)           // [1024] float
#define OFF_NLL  (OFF_LAB + 4096)                     // [1024] float
#define OFF_E    (OFF_NLL + 4096)                     // [1024][512] bf16
#define OFF_WBF  (OFF_E + (size_t)BB*DD*2)            // [50000][512] bf16 normalized
#define NEED_PRE (OFF_WBF + (size_t)CC*DD*2)
#define OFF_INV  OFF_WBF                              // fallback: [50000] float
#define NEED_FB  (OFF_INV + 204800)

// ---------------- kernel 1: normalize embeddings -> bf16 ----------------
__global__ void norm_e_kernel(const float* __restrict__ e, unsigned short* __restrict__ ebf) {
    const int b = blockIdx.x;          // 1024 blocks
    const int l = threadIdx.x;         // 64 threads
    const float4* row = reinterpret_cast<const float4*>(e + (size_t)b * DD);
    float4 v0 = row[l * 2 + 0];
    float4 v1 = row[l * 2 + 1];
    float s = v0.x*v0.x + v0.y*v0.y + v0.z*v0.z + v0.w*v0.w
            + v1.x*v1.x + v1.y*v1.y + v1.z*v1.z + v1.w*v1.w;
    #pragma unroll
    for (int m = 1; m < 64; m <<= 1) s += __shfl_xor(s, m);
    float inv = 1.0f / fmaxf(sqrtf(s), 1e-12f);
    ushort8 h;
    h[0]=f2bf(v0.x*inv); h[1]=f2bf(v0.y*inv); h[2]=f2bf(v0.z*inv); h[3]=f2bf(v0.w*inv);
    h[4]=f2bf(v1.x*inv); h[5]=f2bf(v1.y*inv); h[6]=f2bf(v1.z*inv); h[7]=f2bf(v1.w*inv);
    reinterpret_cast<ushort8*>(ebf + (size_t)b * DD)[l] = h;
}

// ---------------- kernel 2a: normalize weights -> bf16 (PRE path) ----------------
__global__ void wnorm_bf16_kernel(const float* __restrict__ w, unsigned short* __restrict__ wbf) {
    const int row = blockIdx.x * 4 + (threadIdx.x >> 6);   // 12500 blocks * 4 waves
    const int l = threadIdx.x & 63;
    const float4* r = reinterpret_cast<const float4*>(w + (size_t)row * DD);
    float4 v0 = r[l * 2 + 0];
    float4 v1 = r[l * 2 + 1];
    float s = v0.x*v0.x + v0.y*v0.y + v0.z*v0.z + v0.w*v0.w
            + v1.x*v1.x + v1.y*v1.y + v1.z*v1.z + v1.w*v1.w;
    #pragma unroll
    for (int m = 1; m < 64; m <<= 1) s += __shfl_xor(s, m);
    float inv = 1.0f / fmaxf(sqrtf(s), 1e-12f);
    ushort8 h;
    h[0]=f2bf(v0.x*inv); h[1]=f2bf(v0.y*inv); h[2]=f2bf(v0.z*inv); h[3]=f2bf(v0.w*inv);
    h[4]=f2bf(v1.x*inv); h[5]=f2bf(v1.y*inv); h[6]=f2bf(v1.z*inv); h[7]=f2bf(v1.w*inv);
    reinterpret_cast<ushort8*>(wbf + (size_t)row * DD)[l] = h;
}

// ---------------- kernel 2b: weight inverse norms (fallback path) ----------------
__global__ void wnorm_kernel(const float* __restrict__ w, float* __restrict__ invn) {
    const int row = blockIdx.x * 4 + (threadIdx.x >> 6);
    const int l = threadIdx.x & 63;
    const float4* r = reinterpret_cast<const float4*>(w + (size_t)row * DD);
    float4 v0 = r[l * 2 + 0];
    float4 v1 = r[l * 2 + 1];
    float s = v0.x*v0.x + v0.y*v0.y + v0.z*v0.z + v0.w*v0.w
            + v1.x*v1.x + v1.y*v1.y + v1.z*v1.z + v1.w*v1.w;
    #pragma unroll
    for (int m = 1; m < 64; m <<= 1) s += __shfl_xor(s, m);
    if (l == 0) invn[row] = 1.0f / fmaxf(sqrtf(s), 1e-12f);
}

// ---------------- kernel 3: fused GEMM + arcface + partial logsumexp ----------------
// tile: BM=256 x BN=64 x BK=64, 4 waves, double-buffered LDS, 2-phase pipeline.
// LDS per buffer: A = 256*128 B (swizzled), B = 64*128 B (swizzled). 2*40960 = 80 KB.
template<bool PRE>
__global__ __launch_bounds__(256, 2) void arc_gemm_kernel(
        const unsigned short* __restrict__ ebf,  // [1024][512] bf16 normalized
        const unsigned short* __restrict__ wbf,  // [50000][512] bf16 normalized (PRE)
        const float* __restrict__ wgt,           // [50000][512] fp32 raw (fallback)
        const float* __restrict__ invw,          // [50000] (fallback)
        const int* __restrict__ labels,          // [1024]
        float* __restrict__ part_m,              // [1024][NT]
        float* __restrict__ part_s,              // [1024][NT]
        float* __restrict__ lab_logit)           // [1024]
{
    __shared__ __align__(16) char lds[2][40960];

    const int t  = threadIdx.x;
    const int wv = t >> 6;
    const int l  = t & 63;
    const int r16 = l & 15;
    const int kg  = l >> 4;

    // XCD-bijective swizzle: 3128 = 8*391; XCD k owns contiguous bidp range.
    // Within an XCD, m-tile varies fastest -> the 4 blocks sharing a weight
    // tile are consecutive in the same XCD's L2.
    const int bid  = blockIdx.x;
    const int bidp = (bid & 7) * (NBLK / 8) + (bid >> 3);
    const int mt = bidp & 3;        // m-tile 0..3
    const int bn = bidp >> 2;       // n-tile 0..781
    const int m0 = mt * 256;
    const int c0 = bn * 64;

    f32x4 acc[4][4];
    #pragma unroll
    for (int m = 0; m < 4; ++m)
        #pragma unroll
        for (int n = 0; n < 4; ++n)
            acc[m][n] = (f32x4){0.f, 0.f, 0.f, 0.f};

    // ---- staging helpers ----
    auto stageA = [&](int buf, int kt) {
        #pragma unroll
        for (int i = 0; i < 8; ++i) {
            int flat = (i * 256 + t) * 16;
            int row  = flat >> 7;
            int col  = (flat & 127) ^ ((row & 7) << 4);
            const char* src = reinterpret_cast<const char*>(ebf)
                            + (size_t)(m0 + row) * (DD * 2) + kt * 128 + col;
            __builtin_amdgcn_global_load_lds(
                (const __attribute__((address_space(1))) void*)(src),
                (__attribute__((address_space(3))) void*)(&lds[buf][flat]),
                16, 0, 0);
        }
    };
    auto stageB = [&](int buf, int kt) {
        if constexpr (PRE) {
            #pragma unroll
            for (int i = 0; i < 2; ++i) {
                int chunk = i * 256 + t;       // 0..511
                int row   = chunk >> 3;        // class within tile
                int cb    = chunk & 7;
                int cls   = min(c0 + row, CC - 1);   // clamp; masked in epilogue
                int col   = (cb * 16) ^ ((row & 7) << 4);
                const char* src = reinterpret_cast<const char*>(wbf)
                                + (size_t)cls * (DD * 2) + kt * 128 + col;
                __builtin_amdgcn_global_load_lds(
                    (const __attribute__((address_space(1))) void*)(src),
                    (__attribute__((address_space(3))) void*)(&lds[buf][32768 + chunk * 16]),
                    16, 0, 0);
            }
        } else {
            #pragma unroll
            for (int i = 0; i < 2; ++i) {
                int chunk = i * 256 + t;
                int row   = chunk >> 3;
                int cb    = chunk & 7;
                int cls   = c0 + row;
                ushort8 hv = (ushort8){0,0,0,0,0,0,0,0};
                if (cls < CC) {
                    float inv = invw[cls];
                    const float4* src = reinterpret_cast<const float4*>(
                        wgt + (size_t)cls * DD + kt * 64 + cb * 8);
                    float4 f0 = src[0];
                    float4 f1 = src[1];
                    hv[0]=f2bf(f0.x*inv); hv[1]=f2bf(f0.y*inv);
                    hv[2]=f2bf(f0.z*inv); hv[3]=f2bf(f0.w*inv);
                    hv[4]=f2bf(f1.x*inv); hv[5]=f2bf(f1.y*inv);
                    hv[6]=f2bf(f1.z*inv); hv[7]=f2bf(f1.w*inv);
                }
                int dst = 32768 + row * 128 + ((cb * 16) ^ ((row & 7) << 4));
                *reinterpret_cast<ushort8*>(&lds[buf][dst]) = hv;
            }
        }
    };
    auto compute = [&](int buf) {
        #pragma unroll
        for (int kk = 0; kk < 2; ++kk) {
            const int kb = kk * 64 + kg * 16;
            short8 a[4], b[4];
            #pragma unroll
            for (int m = 0; m < 4; ++m) {
                int row = wv * 64 + m * 16 + r16;
                a[m] = *reinterpret_cast<const short8*>(&lds[buf][row * 128 + (kb ^ ((row & 7) << 4))]);
            }
            #pragma unroll
            for (int n = 0; n < 4; ++n) {
                int row = n * 16 + r16;
                b[n] = *reinterpret_cast<const short8*>(&lds[buf][32768 + row * 128 + (kb ^ ((row & 7) << 4))]);
            }
            #pragma unroll
            for (int m = 0; m < 4; ++m)
                #pragma unroll
                for (int n = 0; n < 4; ++n)
                    acc[m][n] = __builtin_amdgcn_mfma_f32_16x16x32_bf16(a[m], b[n], acc[m][n], 0, 0, 0);
        }
    };

    // ---- 2-phase pipelined K-loop (8 K-tiles) ----
    stageA(0, 0); stageB(0, 0);
    __syncthreads();                       // implicit vmcnt(0) drain
    #pragma unroll
    for (int kt = 0; kt < 7; ++kt) {
        const int cur = kt & 1;
        stageA(cur ^ 1, kt + 1);           // issue next-tile loads first
        stageB(cur ^ 1, kt + 1);
        compute(cur);                      // MFMA hides in-flight loads
        __syncthreads();                   // vmcnt(0)+lgkmcnt(0) drain + barrier
    }
    compute(1);

    // ---- epilogue: logits, per-row max + sum(exp) over this 64-col tile ----
    #pragma unroll
    for (int m = 0; m < 4; ++m) {
        #pragma unroll
        for (int j = 0; j < 4; ++j) {
            const int row_local = wv * 64 + m * 16 + kg * 4 + j;
            const int lab = labels[m0 + row_local];
            float vals[4];
            float vmax = -1e30f;
            #pragma unroll
            for (int n = 0; n < 4; ++n) {
                float cosv = acc[m][n][j];
                int col = c0 + n * 16 + r16;
                float logit;
                if (col < CC) {
                    logit = SCALE_F * cosv;
                    if (col == lab) {
                        float c2 = fminf(fmaxf(cosv * cosv, 0.f), 1.f);
                        float phi = cosv * COS_M_F - sqrtf(1.f - c2) * SIN_M_F;
                        phi = (cosv > TH_F) ? phi : (cosv - MM_F);
                        logit = SCALE_F * phi;
                        lab_logit[m0 + row_local] = logit;
                    }
                } else {
                    logit = -1e30f;
                }
                vals[n] = logit;
                vmax = fmaxf(vmax, logit);
            }
            #pragma unroll
            for (int mk = 1; mk < 16; mk <<= 1) vmax = fmaxf(vmax, __shfl_xor(vmax, mk));
            float s = 0.f;
            #pragma unroll
            for (int n = 0; n < 4; ++n) s += __expf(vals[n] - vmax);
            #pragma unroll
            for (int mk = 1; mk < 16; mk <<= 1) s += __shfl_xor(s, mk);
            if (r16 == 0) {
                size_t idx = (size_t)(m0 + row_local) * NT + bn;
                part_m[idx] = vmax;
                part_s[idx] = s;
            }
        }
    }
}

// ---------------- kernel 4: per-row logsumexp merge -> nll ----------------
__global__ void row_lse_kernel(const float* __restrict__ part_m,
                               const float* __restrict__ part_s,
                               const float* __restrict__ lab_logit,
                               float* __restrict__ nll) {
    const int row = blockIdx.x;
    const int t = threadIdx.x;   // 256
    const float* pm = part_m + (size_t)row * NT;
    const float* ps = part_s + (size_t)row * NT;
    float M = -1e30f;
    for (int i = t; i < NT; i += 256) M = fmaxf(M, pm[i]);
    #pragma unroll
    for (int m = 1; m < 64; m <<= 1) M = fmaxf(M, __shfl_xor(M, m));
    __shared__ float redm[4];
    if ((t & 63) == 0) redm[t >> 6] = M;
    __syncthreads();
    M = fmaxf(fmaxf(redm[0], redm[1]), fmaxf(redm[2], redm[3]));
    float S = 0.f;
    for (int i = t; i < NT; i += 256) S += ps[i] * __expf(pm[i] - M);
    #pragma unroll
    for (int m = 1; m < 64; m <<= 1) S += __shfl_xor(S, m);
    __shared__ float reds[4];
    if ((t & 63) == 0) reds[t >> 6] = S;
    __syncthreads();
    if (t == 0) {
        float Sf = reds[0] + reds[1] + reds[2] + reds[3];
        nll[row] = -(lab_logit[row] - M - logf(Sf));
    }
}

// ---------------- kernel 5: mean over 1024 -> scalar ----------------
__global__ void mean_kernel(const float* __restrict__ nll, float* __restrict__ out) {
    const int t = threadIdx.x;  // 1024
    float v = nll[t];
    #pragma unroll
    for (int m = 1; m < 64; m <<= 1) v += __shfl_xor(v, m);
    __shared__ float red[16];
    if ((t & 63) == 0) red[t >> 6] = v;
    __syncthreads();
    if (t == 0) {
        float s = 0.f;
        #pragma unroll
        for (int i = 0; i < 16; ++i) s += red[i];
        out[0] = s * (1.0f / BB);
    }
}

// ---------------- launcher ----------------
extern "C" void kernel_launch(void* const* d_in, const int* in_sizes, int n_in,
                              void* d_out, int out_size, void* d_ws, size_t ws_size,
                              hipStream_t stream) {
    const float* emb    = (const float*)d_in[0];
    const int*   labels = (const int*)d_in[1];
    const float* wgt    = (const float*)d_in[2];
    float* out = (float*)d_out;
    char* ws = (char*)d_ws;

    float* pm     = (float*)(ws + OFF_PM);
    float* ps     = (float*)(ws + OFF_PS);
    float* lablg  = (float*)(ws + OFF_LAB);
    float* nll    = (float*)(ws + OFF_NLL);
    unsigned short* ebf = (unsigned short*)(ws + OFF_E);

    norm_e_kernel<<<BB, 64, 0, stream>>>(emb, ebf);

    if (ws_size >= NEED_PRE) {
        unsigned short* wbf = (unsigned short*)(ws + OFF_WBF);
        wnorm_bf16_kernel<<<CC / 4, 256, 0, stream>>>(wgt, wbf);
        arc_gemm_kernel<true><<<NBLK, 256, 0, stream>>>(
            ebf, wbf, nullptr, nullptr, labels, pm, ps, lablg);
    } else {
        float* invw = (float*)(ws + OFF_INV);
        wnorm_kernel<<<CC / 4, 256, 0, stream>>>(wgt, invw);
        arc_gemm_kernel<false><<<NBLK, 256, 0, stream>>>(
            ebf, nullptr, wgt, invw, labels, pm, ps, lablg);
    }

    row_lse_kernel<<<BB, 256, 0, stream>>>(pm, ps, lablg, nll);
    mean_kernel<<<1, 1024, 0, stream>>>(nll, out);
}